// Round 13
// baseline (288.097 us; speedup 1.0000x reference)
//
#include <hip/hip_runtime.h>
#include <hip/hip_cooperative_groups.h>
namespace cg = cooperative_groups;

#define N_NODES 100000
#define N_EDGES 1600000
#define D_IN 32
#define D_HID 16
#define D_OUT 2

// dst bucketing: 128 nodes per bucket.
#define NPB 128
#define NB 782                       // ceil(100000/128)
#define NROWS (NB * NPB)             // 100096 padded feature rows
#define CHUNK 6400                   // 250 * 6400 = 1,600,000 exactly
#define BBLOCKS 250
#define EPT 13                       // ceil(6400/512); k=12 valid iff tid<256

// Padded per-bucket record windows (mean fill 2046, 11 sigma headroom).
#define PBC 2560
#define DUMMY_SRC 100000u            // zeroed xr feature row; hr[100000]=0
#define DUMMY_REC ((127u << 17) | DUMMY_SRC)

// LESSONS:
//  (r2-5) LDS f32 atomics: ~270 cyc per wave64 op — bulk tile-scatter via
//         LDS atomics is 174-218 µs, all pipes idle.
//  (r7)   Per-edge global atomic reservation + scattered 4B stores:
//         WRITE_SIZE 23->83 MB, 380 µs. Keep LDS-grouped coalesced
//         write-out + bulk per-(block,bucket) reservation.
//  (r8)   Histogram atomicAdd RETURNS the rank: one atomic pass suffices.
//  (r9)   Post-sort, each dst's records are CONTIGUOUS — per-dst lane
//         teams accumulate with plain stores: zero atomics.
//  (r10)  Ballot-based match-any rank REGRESSED: serial ballot+LDS-RMW
//         chain vs pipelined independent atomics. Keep atomic rank.
//  (r11)  Grid < CU count -> 1 block/CU, phase chain exposed.
//  (r12)  But 2 blocks/CU (CHUNK/2) did NOT speed bin: per-CU LDS-pipe
//         work (histogram+placement lane-ops) is partition-invariant and
//         the pipe is shared. Bin is near its structural floor; the
//         remaining fat is the sortacc->acc2 HBM round-trip + launch gap.

__device__ __forceinline__ unsigned bfr(float x) {   // f32 -> bf16 (RNE)
    unsigned u = __float_as_uint(x);
    return (u + 0x7FFFu + ((u >> 16) & 1u)) >> 16;
}
__device__ __forceinline__ float bfu(unsigned lo16) {
    return __uint_as_float(lo16 << 16);
}

// ---------------------------------------------------------------------------
// Fused bin + node-1 transform, single-atomic-pass binning.
// (UNCHANGED from verified round-11 133.9 µs kernel: CHUNK 6400 / 250 blks.)
// ---------------------------------------------------------------------------
__global__ __launch_bounds__(512) void k_bin_node1(
    const int* __restrict__ ei, const float* __restrict__ x,
    const float* __restrict__ w_rel, const float* __restrict__ w_root,
    const float* __restrict__ bb,
    unsigned short* __restrict__ xr, float* __restrict__ agg,
    int* __restrict__ gcur, unsigned* __restrict__ recs2)
{
    __shared__ int cnt[NB];
    __shared__ int loff[NB];
    __shared__ int gbase[NB];
    __shared__ unsigned sorted[CHUNK];           // 25.6 KB
    __shared__ unsigned short bkt16[CHUNK];      // 12.8 KB
    __shared__ float s_rel[D_HID * D_IN];
    __shared__ float s_root[D_HID * D_IN];
    __shared__ float s_b[D_HID];
    int blk = blockIdx.x, tid = threadIdx.x;
    int e0 = blk * CHUNK;

    // ---- batch edge loads (independent, ei read once) ----
    int srcs[EPT], dsts[EPT];
#pragma unroll
    for (int k = 0; k < EPT; k++) {
        int off = tid + k * 512;
        bool ok = off < CHUNK;                   // k==12 -> tid<256
        int e = e0 + off;
        srcs[k] = ok ? ei[e] : 0;
        dsts[k] = ok ? ei[N_EDGES + e] : -1;
    }

    for (int i = tid; i < D_HID * D_IN; i += 512) {
        s_rel[i]  = w_rel[i];
        s_root[i] = w_root[i];
    }
    if (tid < D_HID) s_b[tid] = bb[tid];
    for (int i = tid; i < NB; i += 512) cnt[i] = 0;
    __syncthreads();

    // ---- phase A: histogram + rank in ONE atomic pass ----
    int rank[EPT];
#pragma unroll
    for (int k = 0; k < EPT; k++)
        rank[k] = (dsts[k] >= 0) ? atomicAdd(&cnt[dsts[k] >> 7], 1) : 0;

    // ---- phase B: node-1 transform (independent of A) ----
    int node = blk * 512 + tid;                  // 250*512 = 128000 > 100001
    if (node == N_NODES) {                       // dummy zero xr row
        uint4* xp = (uint4*)(xr + (size_t)node * D_HID);
        xp[0] = make_uint4(0, 0, 0, 0);
        xp[1] = make_uint4(0, 0, 0, 0);
    } else if (node < N_NODES) {
        float row[D_IN];
        const float4* xp = (const float4*)(x + (size_t)node * D_IN);
#pragma unroll
        for (int i = 0; i < D_IN / 4; i++) {
            float4 v = xp[i];
            row[4*i+0] = v.x; row[4*i+1] = v.y; row[4*i+2] = v.z; row[4*i+3] = v.w;
        }
        float oa[D_HID], orr[D_HID];
#pragma unroll
        for (int o = 0; o < D_HID; o++) {
            float a = 0.f, r = s_b[o];
#pragma unroll
            for (int k = 0; k < D_IN; k++) {
                a += row[k] * s_rel[o * D_IN + k];
                r += row[k] * s_root[o * D_IN + k];
            }
            oa[o] = a; orr[o] = r;
        }
        unsigned p[8];
#pragma unroll
        for (int i = 0; i < 8; i++)
            p[i] = bfr(oa[2*i]) | (bfr(oa[2*i+1]) << 16);
        uint4* xrp = (uint4*)(xr + (size_t)node * D_HID);
        xrp[0] = make_uint4(p[0], p[1], p[2], p[3]);
        xrp[1] = make_uint4(p[4], p[5], p[6], p[7]);
        float4* aggp = (float4*)(agg + (size_t)node * D_HID);
#pragma unroll
        for (int i = 0; i < D_HID / 4; i++)
            aggp[i] = make_float4(orr[4*i], orr[4*i+1], orr[4*i+2], orr[4*i+3]);
    }
    __syncthreads();

    // ---- phase C: scan (wave 0) || global reservation (waves 1-7) ----
    if (tid < 64) {
        int running = 0;
        for (int c = 0; c < (NB + 63) / 64; c++) {
            int idx = c * 64 + tid;
            int v = (idx < NB) ? cnt[idx] : 0;
            int incl = v;
#pragma unroll
            for (int off = 1; off < 64; off <<= 1) {
                int t = __shfl_up(incl, off);
                if (tid >= off) incl += t;
            }
            if (idx < NB) loff[idx] = running + incl - v;
            running += __shfl(incl, 63);
        }
    } else {
        for (int i = tid - 64; i < NB; i += 448)
            gbase[i] = (cnt[i] > 0) ? atomicAdd(&gcur[i], cnt[i]) : 0;
    }
    __syncthreads();

    // ---- phase D1: placement at loff+rank, NO atomics ----
#pragma unroll
    for (int k = 0; k < EPT; k++) {
        if (dsts[k] >= 0) {
            int bkt = dsts[k] >> 7;
            int p = loff[bkt] + rank[k];
            sorted[p] = ((unsigned)(dsts[k] & (NPB - 1)) << 17) | (unsigned)srcs[k];
            bkt16[p] = (unsigned short)bkt;
        }
    }
    __syncthreads();

    // ---- phase D2: linear write-out (coalesced runs per bucket) ----
    for (int i = tid; i < CHUNK; i += 512) {
        int b = bkt16[i];
        int idx = gbase[b] + (i - loff[b]);
        if (idx < PBC)                             // 11-sigma overflow guard
            recs2[b * PBC + idx] = sorted[i];
    }
}

// ---------------------------------------------------------------------------
// COOPERATIVE fused sort + L1 accumulate + fold + grid.sync + L2 accumulate.
// One block per bucket, 256 threads, all NB blocks co-resident
// (22 KB LDS, __launch_bounds__(256,4): 4 blocks/CU x 16 waves, cap 1024>=782).
// Phase 1: stage + atomic-rank counting sort (verified r8-r11 structure),
//   4-lane teams x 2 dsts accumulate L1 from LDS, ReLU + layer-2 fold,
//   write hr/outv. NO sorted write-back, NO bbase.
// grid.sync(): hr globally visible.
// Phase 2: 2-lane teams per dst gather hr[src] straight from the STILL-
//   RESIDENT LDS sorted records; plain outv += acc (exclusive rows).
// ---------------------------------------------------------------------------
__global__ __launch_bounds__(256, 4) void k_sortacc2(
    const int* __restrict__ gcur, const unsigned* __restrict__ recs2,
    const unsigned short* __restrict__ srcf, const float* __restrict__ agg,
    const float* __restrict__ w_rel2, const float* __restrict__ w_root2,
    const float* __restrict__ bb2,
    float* __restrict__ hr, float* __restrict__ outv)
{
    __shared__ unsigned stage[PBC];
    __shared__ unsigned sorted[PBC];
    __shared__ int hist[NPB], base[NPB];
    __shared__ float s_rel2[D_OUT * D_HID];
    __shared__ float s_root2[D_OUT * D_HID];
    __shared__ float s_b2[D_OUT];
    int b = blockIdx.x, tid = threadIdx.x;
    int n = min(gcur[b], PBC);
    const unsigned* w = recs2 + (size_t)b * PBC;

    if (tid < D_OUT * D_HID) {
        s_rel2[tid]  = w_rel2[tid];
        s_root2[tid] = w_root2[tid];
    }
    if (tid < D_OUT) s_b2[tid] = bb2[tid];
    if (tid < NPB) hist[tid] = 0;
    for (int i = tid; i < n; i += 256) stage[i] = w[i];
    __syncthreads();

    // ---- rank pass: ONE LDS atomic per record ----
    unsigned rc[PBC / 256];
    int rk[PBC / 256];
#pragma unroll
    for (int j = 0; j < PBC / 256; j++) {
        int i = tid + j * 256;
        if (i < n) {
            rc[j] = stage[i];
            rk[j] = atomicAdd(&hist[rc[j] >> 17], 1);
        } else {
            rc[j] = DUMMY_REC; rk[j] = -1;
        }
    }
    __syncthreads();

    // ---- wave-0 shuffle scan of 128 bins -> exclusive base ----
    if (tid < 64) {
        int v0 = hist[tid], v1 = hist[tid + 64];
        int s0 = v0, s1 = v1;
#pragma unroll
        for (int off = 1; off < 64; off <<= 1) {
            int t0 = __shfl_up(s0, off);
            int t1 = __shfl_up(s1, off);
            if (tid >= off) { s0 += t0; s1 += t1; }
        }
        int tot0 = __shfl(s0, 63);
        base[tid]      = s0 - v0;
        base[tid + 64] = tot0 + s1 - v1;
    }
    __syncthreads();

    // ---- placement, NO atomics ----
#pragma unroll
    for (int j = 0; j < PBC / 256; j++) {
        if (rk[j] >= 0)
            sorted[base[rc[j] >> 17] + rk[j]] = rc[j];
    }
    __syncthreads();

    // ---- phase 1 accumulate: 64 four-lane teams x 2 dsts, zero atomics ----
    int t4 = tid >> 2, l = tid & 3;
#pragma unroll
    for (int half = 0; half < 2; half++) {
        int t = t4 + half * 64;
        int node = b * NPB + t;
        int cbase = base[t], c = hist[t];
        float acc0 = 0.f, acc1 = 0.f, acc2_ = 0.f, acc3 = 0.f;
        if (node < N_NODES) {
            const float4 r4 = *(const float4*)(agg + (size_t)node * D_HID + l * 4);
            acc0 = r4.x; acc1 = r4.y; acc2_ = r4.z; acc3 = r4.w;
        }
        for (int r0 = 0; r0 < c; r0 += 8) {
            int m = c - r0;
            uint2 vv[8];
#pragma unroll
            for (int j = 0; j < 8; j++) {
                unsigned src = (j < m) ? (sorted[cbase + r0 + j] & 0x1FFFF) : DUMMY_SRC;
                vv[j] = *(const uint2*)(srcf + (size_t)src * D_HID + l * 4);
            }
#pragma unroll
            for (int j = 0; j < 8; j++) {
                acc0 += bfu(vv[j].x & 0xFFFFu); acc1 += bfu(vv[j].x >> 16);
                acc2_ += bfu(vv[j].y & 0xFFFFu); acc3 += bfu(vv[j].y >> 16);
            }
        }

        // ReLU + layer-2 fold on the in-register row
        float h0 = fmaxf(acc0, 0.f), h1 = fmaxf(acc1, 0.f);
        float h2 = fmaxf(acc2_, 0.f), h3 = fmaxf(acc3, 0.f);
        float pr[D_OUT], pp[D_OUT];
#pragma unroll
        for (int o = 0; o < D_OUT; o++) {
            const float* wr = &s_rel2[o * D_HID + l * 4];
            const float* wo = &s_root2[o * D_HID + l * 4];
            pr[o] = h0 * wr[0] + h1 * wr[1] + h2 * wr[2] + h3 * wr[3];
            pp[o] = h0 * wo[0] + h1 * wo[1] + h2 * wo[2] + h3 * wo[3];
        }
#pragma unroll
        for (int m = 1; m < 4; m <<= 1) {
            pr[0] += __shfl_xor(pr[0], m); pr[1] += __shfl_xor(pr[1], m);
            pp[0] += __shfl_xor(pp[0], m); pp[1] += __shfl_xor(pp[1], m);
        }
        if (l == 0) {
            if (node < N_NODES) {
                ((float2*)hr)[node]   = make_float2(pr[0], pr[1]);
                ((float2*)outv)[node] = make_float2(pp[0] + s_b2[0], pp[1] + s_b2[1]);
            } else if (node == N_NODES) {
                ((float2*)hr)[node] = make_float2(0.f, 0.f);   // dummy row
            }
        }
    }

    // ---- make hr/outv globally visible, then grid-wide barrier ----
    __threadfence();
    cg::this_grid().sync();

    // ---- phase 2: layer-2 accumulate from LDS-resident sorted records ----
    int t2 = tid >> 1, l2 = tid & 1;
    int cbase2 = base[t2], c2 = hist[t2];
    int node2 = b * NPB + t2;
    float acc = 0.f;
    for (int r0 = 0; r0 < c2; r0 += 8) {
        int m = c2 - r0;
        float vv[8];
#pragma unroll
        for (int j = 0; j < 8; j++) {
            unsigned src = (j < m) ? (sorted[cbase2 + r0 + j] & 0x1FFFF) : DUMMY_SRC;
            vv[j] = hr[(size_t)src * D_OUT + l2];
        }
#pragma unroll
        for (int j = 0; j < 8; j++) acc += vv[j];
    }
    if (node2 < N_NODES)
        outv[(size_t)node2 * D_OUT + l2] += acc;   // exclusive: plain RMW
}

extern "C" void kernel_launch(void* const* d_in, const int* in_sizes, int n_in,
                              void* d_out, int out_size, void* d_ws, size_t ws_size,
                              hipStream_t stream) {
    const float* x       = (const float*)d_in[0];
    const int*   ei      = (const int*)  d_in[1];
    const float* w1_rel  = (const float*)d_in[2];
    const float* w1_root = (const float*)d_in[3];
    const float* b1      = (const float*)d_in[4];
    const float* w2_rel  = (const float*)d_in[5];
    const float* w2_root = (const float*)d_in[6];
    const float* b2      = (const float*)d_in[7];
    float* out = (float*)d_out;

    // Workspace (~18.5 MB; everything rewritten each call):
    float*          agg   = (float*)d_ws;                                   // NROWS*16 f32 (6.4 MB)
    unsigned short* xrh   = (unsigned short*)(agg + (size_t)NROWS * D_HID); // NROWS*16 bf16 (3.2 MB)
    unsigned*       recs2 = (unsigned*)(xrh + (size_t)NROWS * D_HID);       // NB*PBC (8.0 MB)
    float*          hr    = (float*)(recs2 + (size_t)NB * PBC);             // NROWS*2 f32 (0.8 MB)
    int*            gcur  = (int*)(hr + (size_t)NROWS * D_OUT);             // NB

    hipMemsetAsync(gcur, 0, NB * sizeof(int), stream);

    k_bin_node1<<<dim3(BBLOCKS), dim3(512), 0, stream>>>(
        ei, x, w1_rel, w1_root, b1, xrh, agg, gcur, recs2);

    // Cooperative fused sort+acc (needs all NB blocks co-resident).
    {
        const int* a_gcur = gcur;
        const unsigned* a_recs2 = recs2;
        const unsigned short* a_srcf = xrh;
        const float* a_agg = agg;
        const float* a_wr = w2_rel;
        const float* a_wo = w2_root;
        const float* a_b2 = b2;
        float* a_hr = hr;
        float* a_out = out;
        void* args[] = { (void*)&a_gcur, (void*)&a_recs2, (void*)&a_srcf,
                         (void*)&a_agg, (void*)&a_wr, (void*)&a_wo,
                         (void*)&a_b2, (void*)&a_hr, (void*)&a_out };
        hipLaunchCooperativeKernel((const void*)k_sortacc2,
                                   dim3(NB), dim3(256), args, 0, stream);
    }
}

// Round 14
// 132.759 us; speedup vs baseline: 2.1701x; 2.1701x over previous
//
#include <hip/hip_runtime.h>

#define N_NODES 100000
#define N_EDGES 1600000
#define D_IN 32
#define D_HID 16
#define D_OUT 2

// dst bucketing: 128 nodes per bucket.
#define NPB 128
#define NB 782                       // ceil(100000/128)
#define NROWS (NB * NPB)             // 100096 padded feature rows
#define CHUNK 6400                   // 250 * 6400 = 1,600,000 exactly
#define BBLOCKS 250
#define EPT 13                       // ceil(6400/512); k=12 valid iff tid<256

// Padded per-bucket record windows (mean fill 2046, 11 sigma headroom).
#define PBC 2560
#define DUMMY_SRC 100000u            // zeroed xr feature row; hr[100000]=0
#define DUMMY_REC ((127u << 17) | DUMMY_SRC)

// LESSONS:
//  (r2-5) LDS f32 atomics: ~270 cyc per wave64 op — bulk tile-scatter via
//         LDS atomics is 174-218 µs, all pipes idle.
//  (r7)   Per-edge global atomic reservation + scattered 4B stores:
//         WRITE_SIZE 23->83 MB, 380 µs. Keep LDS-grouped coalesced
//         write-out + bulk per-(block,bucket) reservation.
//  (r8)   Histogram atomicAdd RETURNS the rank: one atomic pass suffices.
//  (r9)   Post-sort, each dst's records are CONTIGUOUS — per-dst lane
//         teams accumulate with plain stores: zero atomics.
//  (r10)  Ballot-based match-any rank REGRESSED: serial ballot+LDS-RMW
//         chain vs pipelined independent atomics. Keep atomic rank.
//  (r11/12) Grid sizing: <1 block/CU exposes the phase chain, but 2
//         blocks/CU doesn't help either — per-CU LDS-pipe work is
//         partition-invariant. Bin is near its structural floor.
//  (r13)  Cooperative grid.sync fusion REGRESSED 2x: forced co-residency
//         kills block-turnover pipelining; the most-loaded CU paces the
//         whole grid. A second launch (~2 µs) is cheaper. Also: LDS
//         staging that the SAME thread writes then reads at the SAME
//         index is a pure pass-through — keep such records in registers.

__device__ __forceinline__ unsigned bfr(float x) {   // f32 -> bf16 (RNE)
    unsigned u = __float_as_uint(x);
    return (u + 0x7FFFu + ((u >> 16) & 1u)) >> 16;
}
__device__ __forceinline__ float bfu(unsigned lo16) {
    return __uint_as_float(lo16 << 16);
}

// ---------------------------------------------------------------------------
// Fused bin + node-1 transform, single-atomic-pass binning.
// (UNCHANGED from verified round-11 133.9 µs kernel.)
// ---------------------------------------------------------------------------
__global__ __launch_bounds__(512) void k_bin_node1(
    const int* __restrict__ ei, const float* __restrict__ x,
    const float* __restrict__ w_rel, const float* __restrict__ w_root,
    const float* __restrict__ bb,
    unsigned short* __restrict__ xr, float* __restrict__ agg,
    int* __restrict__ gcur, unsigned* __restrict__ recs2)
{
    __shared__ int cnt[NB];
    __shared__ int loff[NB];
    __shared__ int gbase[NB];
    __shared__ unsigned sorted[CHUNK];           // 25.6 KB
    __shared__ unsigned short bkt16[CHUNK];      // 12.8 KB
    __shared__ float s_rel[D_HID * D_IN];
    __shared__ float s_root[D_HID * D_IN];
    __shared__ float s_b[D_HID];
    int blk = blockIdx.x, tid = threadIdx.x;
    int e0 = blk * CHUNK;

    // ---- batch edge loads (independent, ei read once) ----
    int srcs[EPT], dsts[EPT];
#pragma unroll
    for (int k = 0; k < EPT; k++) {
        int off = tid + k * 512;
        bool ok = off < CHUNK;                   // k==12 -> tid<256
        int e = e0 + off;
        srcs[k] = ok ? ei[e] : 0;
        dsts[k] = ok ? ei[N_EDGES + e] : -1;
    }

    for (int i = tid; i < D_HID * D_IN; i += 512) {
        s_rel[i]  = w_rel[i];
        s_root[i] = w_root[i];
    }
    if (tid < D_HID) s_b[tid] = bb[tid];
    for (int i = tid; i < NB; i += 512) cnt[i] = 0;
    __syncthreads();

    // ---- phase A: histogram + rank in ONE atomic pass ----
    int rank[EPT];
#pragma unroll
    for (int k = 0; k < EPT; k++)
        rank[k] = (dsts[k] >= 0) ? atomicAdd(&cnt[dsts[k] >> 7], 1) : 0;

    // ---- phase B: node-1 transform (independent of A) ----
    int node = blk * 512 + tid;                  // 250*512 = 128000 > 100001
    if (node == N_NODES) {                       // dummy zero xr row
        uint4* xp = (uint4*)(xr + (size_t)node * D_HID);
        xp[0] = make_uint4(0, 0, 0, 0);
        xp[1] = make_uint4(0, 0, 0, 0);
    } else if (node < N_NODES) {
        float row[D_IN];
        const float4* xp = (const float4*)(x + (size_t)node * D_IN);
#pragma unroll
        for (int i = 0; i < D_IN / 4; i++) {
            float4 v = xp[i];
            row[4*i+0] = v.x; row[4*i+1] = v.y; row[4*i+2] = v.z; row[4*i+3] = v.w;
        }
        float oa[D_HID], orr[D_HID];
#pragma unroll
        for (int o = 0; o < D_HID; o++) {
            float a = 0.f, r = s_b[o];
#pragma unroll
            for (int k = 0; k < D_IN; k++) {
                a += row[k] * s_rel[o * D_IN + k];
                r += row[k] * s_root[o * D_IN + k];
            }
            oa[o] = a; orr[o] = r;
        }
        unsigned p[8];
#pragma unroll
        for (int i = 0; i < 8; i++)
            p[i] = bfr(oa[2*i]) | (bfr(oa[2*i+1]) << 16);
        uint4* xrp = (uint4*)(xr + (size_t)node * D_HID);
        xrp[0] = make_uint4(p[0], p[1], p[2], p[3]);
        xrp[1] = make_uint4(p[4], p[5], p[6], p[7]);
        float4* aggp = (float4*)(agg + (size_t)node * D_HID);
#pragma unroll
        for (int i = 0; i < D_HID / 4; i++)
            aggp[i] = make_float4(orr[4*i], orr[4*i+1], orr[4*i+2], orr[4*i+3]);
    }
    __syncthreads();

    // ---- phase C: scan (wave 0) || global reservation (waves 1-7) ----
    if (tid < 64) {
        int running = 0;
        for (int c = 0; c < (NB + 63) / 64; c++) {
            int idx = c * 64 + tid;
            int v = (idx < NB) ? cnt[idx] : 0;
            int incl = v;
#pragma unroll
            for (int off = 1; off < 64; off <<= 1) {
                int t = __shfl_up(incl, off);
                if (tid >= off) incl += t;
            }
            if (idx < NB) loff[idx] = running + incl - v;
            running += __shfl(incl, 63);
        }
    } else {
        for (int i = tid - 64; i < NB; i += 448)
            gbase[i] = (cnt[i] > 0) ? atomicAdd(&gcur[i], cnt[i]) : 0;
    }
    __syncthreads();

    // ---- phase D1: placement at loff+rank, NO atomics ----
#pragma unroll
    for (int k = 0; k < EPT; k++) {
        if (dsts[k] >= 0) {
            int bkt = dsts[k] >> 7;
            int p = loff[bkt] + rank[k];
            sorted[p] = ((unsigned)(dsts[k] & (NPB - 1)) << 17) | (unsigned)srcs[k];
            bkt16[p] = (unsigned short)bkt;
        }
    }
    __syncthreads();

    // ---- phase D2: linear write-out (coalesced runs per bucket) ----
    for (int i = tid; i < CHUNK; i += 512) {
        int b = bkt16[i];
        int idx = gbase[b] + (i - loff[b]);
        if (idx < PBC)                             // 11-sigma overflow guard
            recs2[b * PBC + idx] = sorted[i];
    }
}

// ---------------------------------------------------------------------------
// Fused per-bucket sort + layer-1 accumulate + ReLU + layer-2 weight fold.
// Same as verified r11 kernel EXCEPT: the stage[] LDS pass-through is gone —
// records load global->register directly at kernel top (5 independent loads
// in flight under setup), r13 lesson. LDS 22 -> 11.5 KB.
// ---------------------------------------------------------------------------
__global__ __launch_bounds__(512) void k_sortacc(
    const int* __restrict__ gcur, unsigned* __restrict__ recs2,
    const unsigned short* __restrict__ srcf, const float* __restrict__ agg,
    const float* __restrict__ w_rel2, const float* __restrict__ w_root2,
    const float* __restrict__ bb2,
    float* __restrict__ hr, float* __restrict__ outv,
    unsigned* __restrict__ bbase)
{
    __shared__ unsigned sorted[PBC];
    __shared__ int hist[NPB], base[NPB];
    __shared__ float s_rel2[D_OUT * D_HID];
    __shared__ float s_root2[D_OUT * D_HID];
    __shared__ float s_b2[D_OUT];
    int b = blockIdx.x, tid = threadIdx.x;
    int n = min(gcur[b], PBC);
    unsigned* w = recs2 + (size_t)b * PBC;

    // ---- batch record loads global->reg (replaces stage[] pass-through) ----
    unsigned rc[PBC / 512];
#pragma unroll
    for (int j = 0; j < PBC / 512; j++) {
        int i = tid + j * 512;
        rc[j] = (i < n) ? w[i] : DUMMY_REC;
    }

    // ---- hoisted: this thread's team row of agg (used only in epilogue) ----
    int t = tid >> 2, l = tid & 3;
    int node = b * NPB + t;
    float acc0 = 0.f, acc1 = 0.f, acc2_ = 0.f, acc3 = 0.f;
    if (node < N_NODES) {
        const float4 r4 = *(const float4*)(agg + (size_t)node * D_HID + l * 4);
        acc0 = r4.x; acc1 = r4.y; acc2_ = r4.z; acc3 = r4.w;
    }

    if (tid < D_OUT * D_HID) {
        s_rel2[tid]  = w_rel2[tid];
        s_root2[tid] = w_root2[tid];
    }
    if (tid < D_OUT) s_b2[tid] = bb2[tid];
    if (tid < NPB) hist[tid] = 0;
    __syncthreads();

    // ---- rank pass: ONE LDS atomic per record ----
    int rk[PBC / 512];
#pragma unroll
    for (int j = 0; j < PBC / 512; j++) {
        int i = tid + j * 512;
        rk[j] = (i < n) ? atomicAdd(&hist[rc[j] >> 17], 1) : -1;
    }
    __syncthreads();

    // ---- wave-0 shuffle scan of 128 bins -> exclusive base ----
    if (tid < 64) {
        int v0 = hist[tid], v1 = hist[tid + 64];
        int s0 = v0, s1 = v1;
#pragma unroll
        for (int off = 1; off < 64; off <<= 1) {
            int t0 = __shfl_up(s0, off);
            int t1 = __shfl_up(s1, off);
            if (tid >= off) { s0 += t0; s1 += t1; }
        }
        int tot0 = __shfl(s0, 63);
        base[tid]      = s0 - v0;
        base[tid + 64] = tot0 + s1 - v1;
    }
    __syncthreads();

    // ---- placement, NO atomics ----
#pragma unroll
    for (int j = 0; j < PBC / 512; j++) {
        if (rk[j] >= 0)
            sorted[base[rc[j] >> 17] + rk[j]] = rc[j];
    }
    __syncthreads();

    // write back sorted (coalesced) + per-dst (base,cnt) for k_acc2
    for (int i = tid; i < n; i += 512) w[i] = sorted[i];
    if (tid < NPB)
        bbase[b * NPB + tid] = (unsigned)base[tid] | ((unsigned)hist[tid] << 16);

    // ---- per-dst team accumulate: 4 lanes/team, zero atomics ----
    int cbase = base[t], c = hist[t];
    for (int r0 = 0; r0 < c; r0 += 8) {
        int m = c - r0;
        uint2 vv[8];
#pragma unroll
        for (int j = 0; j < 8; j++) {
            unsigned src = (j < m) ? (sorted[cbase + r0 + j] & 0x1FFFF) : DUMMY_SRC;
            vv[j] = *(const uint2*)(srcf + (size_t)src * D_HID + l * 4);
        }
#pragma unroll
        for (int j = 0; j < 8; j++) {
            acc0 += bfu(vv[j].x & 0xFFFFu); acc1 += bfu(vv[j].x >> 16);
            acc2_ += bfu(vv[j].y & 0xFFFFu); acc3 += bfu(vv[j].y >> 16);
        }
    }

    // ---- ReLU + layer-2 fold on the in-register row ----
    float h0 = fmaxf(acc0, 0.f), h1 = fmaxf(acc1, 0.f);
    float h2 = fmaxf(acc2_, 0.f), h3 = fmaxf(acc3, 0.f);
    float pr[D_OUT], pp[D_OUT];
#pragma unroll
    for (int o = 0; o < D_OUT; o++) {
        const float* wr = &s_rel2[o * D_HID + l * 4];
        const float* wo = &s_root2[o * D_HID + l * 4];
        pr[o] = h0 * wr[0] + h1 * wr[1] + h2 * wr[2] + h3 * wr[3];
        pp[o] = h0 * wo[0] + h1 * wo[1] + h2 * wo[2] + h3 * wo[3];
    }
#pragma unroll
    for (int m = 1; m < 4; m <<= 1) {
        pr[0] += __shfl_xor(pr[0], m); pr[1] += __shfl_xor(pr[1], m);
        pp[0] += __shfl_xor(pp[0], m); pp[1] += __shfl_xor(pp[1], m);
    }
    if (l == 0) {
        if (node < N_NODES) {
            ((float2*)hr)[node]   = make_float2(pr[0], pr[1]);
            ((float2*)outv)[node] = make_float2(pp[0] + s_b2[0], pp[1] + s_b2[1]);
        } else if (node == N_NODES) {
            ((float2*)hr)[node] = make_float2(0.f, 0.f);   // dummy row
        }
    }
}

// ---------------------------------------------------------------------------
// Layer-2 accumulate: one block per bucket, one 2-lane team per dst.
// (UNCHANGED from verified round-11 133.9 µs kernel.)
// ---------------------------------------------------------------------------
__global__ __launch_bounds__(256) void k_acc2(
    const unsigned* __restrict__ recs2, const unsigned* __restrict__ bbase,
    const float* __restrict__ hr, float* __restrict__ outv)
{
    __shared__ unsigned srt[PBC];
    int b = blockIdx.x, tid = threadIdx.x;
    unsigned pk127 = bbase[b * NPB + 127];
    int n = (int)(pk127 & 0xFFFFu) + (int)(pk127 >> 16);
    const unsigned* rp = recs2 + (size_t)b * PBC;
    for (int i = tid; i < n; i += 256) srt[i] = rp[i];

    int t = tid >> 1, l = tid & 1;
    unsigned pk = bbase[b * NPB + t];
    int cbase = (int)(pk & 0xFFFFu), c = (int)(pk >> 16);
    int node = b * NPB + t;
    __syncthreads();

    float acc = 0.f;
    for (int r0 = 0; r0 < c; r0 += 8) {
        int m = c - r0;
        float vv[8];
#pragma unroll
        for (int j = 0; j < 8; j++) {
            unsigned src = (j < m) ? (srt[cbase + r0 + j] & 0x1FFFF) : DUMMY_SRC;
            vv[j] = hr[(size_t)src * D_OUT + l];
        }
#pragma unroll
        for (int j = 0; j < 8; j++) acc += vv[j];
    }
    if (node < N_NODES)
        outv[(size_t)node * D_OUT + l] += acc;     // exclusive: plain RMW
}

extern "C" void kernel_launch(void* const* d_in, const int* in_sizes, int n_in,
                              void* d_out, int out_size, void* d_ws, size_t ws_size,
                              hipStream_t stream) {
    const float* x       = (const float*)d_in[0];
    const int*   ei      = (const int*)  d_in[1];
    const float* w1_rel  = (const float*)d_in[2];
    const float* w1_root = (const float*)d_in[3];
    const float* b1      = (const float*)d_in[4];
    const float* w2_rel  = (const float*)d_in[5];
    const float* w2_root = (const float*)d_in[6];
    const float* b2      = (const float*)d_in[7];
    float* out = (float*)d_out;

    // Workspace (~19 MB; everything rewritten each call):
    float*          agg   = (float*)d_ws;                                   // NROWS*16 f32 (6.4 MB)
    unsigned short* xrh   = (unsigned short*)(agg + (size_t)NROWS * D_HID); // NROWS*16 bf16 (3.2 MB)
    unsigned*       recs2 = (unsigned*)(xrh + (size_t)NROWS * D_HID);       // NB*PBC (8.0 MB)
    float*          hr    = (float*)(recs2 + (size_t)NB * PBC);             // NROWS*2 f32 (0.8 MB)
    unsigned*       bbase = (unsigned*)(hr + (size_t)NROWS * D_OUT);        // NROWS u32 (0.4 MB)
    int*            gcur  = (int*)(bbase + (size_t)NROWS);                  // NB

    hipMemsetAsync(gcur, 0, NB * sizeof(int), stream);

    k_bin_node1<<<dim3(BBLOCKS), dim3(512), 0, stream>>>(
        ei, x, w1_rel, w1_root, b1, xrh, agg, gcur, recs2);

    k_sortacc<<<dim3(NB), dim3(512), 0, stream>>>(
        gcur, recs2, xrh, agg, w2_rel, w2_root, b2, hr, out, bbase);

    k_acc2<<<dim3(NB), dim3(256), 0, stream>>>(recs2, bbase, hr, out);
}

// Round 15
// 132.194 us; speedup vs baseline: 2.1793x; 1.0043x over previous
//
#include <hip/hip_runtime.h>

#define N_NODES 100000
#define N_EDGES 1600000
#define D_IN 32
#define D_HID 16
#define D_OUT 2

// dst bucketing: 128 nodes per bucket.
#define NPB 128
#define NB 782                       // ceil(100000/128)
#define NROWS (NB * NPB)             // 100096 padded feature rows
#define CHUNK 6400                   // 250 * 6400 = 1,600,000 exactly
#define BBLOCKS 250
#define EPT 13                       // ceil(6400/512); k=12 valid iff tid<256

// Padded per-bucket record windows (mean fill 2046, 11 sigma headroom).
#define PBC 2560
#define DUMMY_SRC 100000u            // zeroed xr feature row; hr[100000]=0
#define DUMMY_REC ((127u << 17) | DUMMY_SRC)

// LESSONS:
//  (r2-5) LDS f32 atomics: ~270 cyc per wave64 op — bulk tile-scatter via
//         LDS atomics is 174-218 µs, all pipes idle.
//  (r7)   Per-edge global atomic reservation + scattered 4B stores:
//         WRITE_SIZE 23->83 MB, 380 µs. Keep LDS-grouped coalesced
//         write-out + bulk per-(block,bucket) reservation.
//  (r8)   Histogram atomicAdd RETURNS the rank: one atomic pass suffices.
//  (r9)   Post-sort, each dst's records are CONTIGUOUS — per-dst lane
//         teams accumulate with plain stores: zero atomics.
//  (r10)  Ballot-based match-any rank REGRESSED: serial ballot+LDS-RMW
//         chain vs pipelined independent atomics. Keep atomic rank.
//  (r11/12) Grid sizing: <1 block/CU exposes the phase chain, but 2
//         blocks/CU doesn't help either — per-CU LDS-pipe work is
//         partition-invariant. Bin is near its structural floor.
//  (r13)  Cooperative grid.sync fusion REGRESSED 2x: forced co-residency
//         kills block-turnover pipelining. A second launch is cheaper.
//         LDS staging that the same thread writes then reads at the same
//         index is a pure pass-through — keep records in registers.
//  (r14)  Contiguous-run consumers don't need LDS staging at all: read
//         the run directly from global (coalesced within team) — saves
//         the stage pass AND the barrier (more cross-kernel overlap).

__device__ __forceinline__ unsigned bfr(float x) {   // f32 -> bf16 (RNE)
    unsigned u = __float_as_uint(x);
    return (u + 0x7FFFu + ((u >> 16) & 1u)) >> 16;
}
__device__ __forceinline__ float bfu(unsigned lo16) {
    return __uint_as_float(lo16 << 16);
}

// ---------------------------------------------------------------------------
// Fused bin + node-1 transform, single-atomic-pass binning.
// (UNCHANGED from verified round-14 132.8 µs kernel.)
// ---------------------------------------------------------------------------
__global__ __launch_bounds__(512) void k_bin_node1(
    const int* __restrict__ ei, const float* __restrict__ x,
    const float* __restrict__ w_rel, const float* __restrict__ w_root,
    const float* __restrict__ bb,
    unsigned short* __restrict__ xr, float* __restrict__ agg,
    int* __restrict__ gcur, unsigned* __restrict__ recs2)
{
    __shared__ int cnt[NB];
    __shared__ int loff[NB];
    __shared__ int gbase[NB];
    __shared__ unsigned sorted[CHUNK];           // 25.6 KB
    __shared__ unsigned short bkt16[CHUNK];      // 12.8 KB
    __shared__ float s_rel[D_HID * D_IN];
    __shared__ float s_root[D_HID * D_IN];
    __shared__ float s_b[D_HID];
    int blk = blockIdx.x, tid = threadIdx.x;
    int e0 = blk * CHUNK;

    // ---- batch edge loads (independent, ei read once) ----
    int srcs[EPT], dsts[EPT];
#pragma unroll
    for (int k = 0; k < EPT; k++) {
        int off = tid + k * 512;
        bool ok = off < CHUNK;                   // k==12 -> tid<256
        int e = e0 + off;
        srcs[k] = ok ? ei[e] : 0;
        dsts[k] = ok ? ei[N_EDGES + e] : -1;
    }

    for (int i = tid; i < D_HID * D_IN; i += 512) {
        s_rel[i]  = w_rel[i];
        s_root[i] = w_root[i];
    }
    if (tid < D_HID) s_b[tid] = bb[tid];
    for (int i = tid; i < NB; i += 512) cnt[i] = 0;
    __syncthreads();

    // ---- phase A: histogram + rank in ONE atomic pass ----
    int rank[EPT];
#pragma unroll
    for (int k = 0; k < EPT; k++)
        rank[k] = (dsts[k] >= 0) ? atomicAdd(&cnt[dsts[k] >> 7], 1) : 0;

    // ---- phase B: node-1 transform (independent of A) ----
    int node = blk * 512 + tid;                  // 250*512 = 128000 > 100001
    if (node == N_NODES) {                       // dummy zero xr row
        uint4* xp = (uint4*)(xr + (size_t)node * D_HID);
        xp[0] = make_uint4(0, 0, 0, 0);
        xp[1] = make_uint4(0, 0, 0, 0);
    } else if (node < N_NODES) {
        float row[D_IN];
        const float4* xp = (const float4*)(x + (size_t)node * D_IN);
#pragma unroll
        for (int i = 0; i < D_IN / 4; i++) {
            float4 v = xp[i];
            row[4*i+0] = v.x; row[4*i+1] = v.y; row[4*i+2] = v.z; row[4*i+3] = v.w;
        }
        float oa[D_HID], orr[D_HID];
#pragma unroll
        for (int o = 0; o < D_HID; o++) {
            float a = 0.f, r = s_b[o];
#pragma unroll
            for (int k = 0; k < D_IN; k++) {
                a += row[k] * s_rel[o * D_IN + k];
                r += row[k] * s_root[o * D_IN + k];
            }
            oa[o] = a; orr[o] = r;
        }
        unsigned p[8];
#pragma unroll
        for (int i = 0; i < 8; i++)
            p[i] = bfr(oa[2*i]) | (bfr(oa[2*i+1]) << 16);
        uint4* xrp = (uint4*)(xr + (size_t)node * D_HID);
        xrp[0] = make_uint4(p[0], p[1], p[2], p[3]);
        xrp[1] = make_uint4(p[4], p[5], p[6], p[7]);
        float4* aggp = (float4*)(agg + (size_t)node * D_HID);
#pragma unroll
        for (int i = 0; i < D_HID / 4; i++)
            aggp[i] = make_float4(orr[4*i], orr[4*i+1], orr[4*i+2], orr[4*i+3]);
    }
    __syncthreads();

    // ---- phase C: scan (wave 0) || global reservation (waves 1-7) ----
    if (tid < 64) {
        int running = 0;
        for (int c = 0; c < (NB + 63) / 64; c++) {
            int idx = c * 64 + tid;
            int v = (idx < NB) ? cnt[idx] : 0;
            int incl = v;
#pragma unroll
            for (int off = 1; off < 64; off <<= 1) {
                int t = __shfl_up(incl, off);
                if (tid >= off) incl += t;
            }
            if (idx < NB) loff[idx] = running + incl - v;
            running += __shfl(incl, 63);
        }
    } else {
        for (int i = tid - 64; i < NB; i += 448)
            gbase[i] = (cnt[i] > 0) ? atomicAdd(&gcur[i], cnt[i]) : 0;
    }
    __syncthreads();

    // ---- phase D1: placement at loff+rank, NO atomics ----
#pragma unroll
    for (int k = 0; k < EPT; k++) {
        if (dsts[k] >= 0) {
            int bkt = dsts[k] >> 7;
            int p = loff[bkt] + rank[k];
            sorted[p] = ((unsigned)(dsts[k] & (NPB - 1)) << 17) | (unsigned)srcs[k];
            bkt16[p] = (unsigned short)bkt;
        }
    }
    __syncthreads();

    // ---- phase D2: linear write-out (coalesced runs per bucket) ----
    for (int i = tid; i < CHUNK; i += 512) {
        int b = bkt16[i];
        int idx = gbase[b] + (i - loff[b]);
        if (idx < PBC)                             // 11-sigma overflow guard
            recs2[b * PBC + idx] = sorted[i];
    }
}

// ---------------------------------------------------------------------------
// Fused per-bucket sort + layer-1 accumulate + ReLU + layer-2 weight fold.
// (UNCHANGED from verified round-14 132.8 µs kernel.)
// ---------------------------------------------------------------------------
__global__ __launch_bounds__(512) void k_sortacc(
    const int* __restrict__ gcur, unsigned* __restrict__ recs2,
    const unsigned short* __restrict__ srcf, const float* __restrict__ agg,
    const float* __restrict__ w_rel2, const float* __restrict__ w_root2,
    const float* __restrict__ bb2,
    float* __restrict__ hr, float* __restrict__ outv,
    unsigned* __restrict__ bbase)
{
    __shared__ unsigned sorted[PBC];
    __shared__ int hist[NPB], base[NPB];
    __shared__ float s_rel2[D_OUT * D_HID];
    __shared__ float s_root2[D_OUT * D_HID];
    __shared__ float s_b2[D_OUT];
    int b = blockIdx.x, tid = threadIdx.x;
    int n = min(gcur[b], PBC);
    unsigned* w = recs2 + (size_t)b * PBC;

    // ---- batch record loads global->reg (replaces stage[] pass-through) ----
    unsigned rc[PBC / 512];
#pragma unroll
    for (int j = 0; j < PBC / 512; j++) {
        int i = tid + j * 512;
        rc[j] = (i < n) ? w[i] : DUMMY_REC;
    }

    // ---- hoisted: this thread's team row of agg (used only in epilogue) ----
    int t = tid >> 2, l = tid & 3;
    int node = b * NPB + t;
    float acc0 = 0.f, acc1 = 0.f, acc2_ = 0.f, acc3 = 0.f;
    if (node < N_NODES) {
        const float4 r4 = *(const float4*)(agg + (size_t)node * D_HID + l * 4);
        acc0 = r4.x; acc1 = r4.y; acc2_ = r4.z; acc3 = r4.w;
    }

    if (tid < D_OUT * D_HID) {
        s_rel2[tid]  = w_rel2[tid];
        s_root2[tid] = w_root2[tid];
    }
    if (tid < D_OUT) s_b2[tid] = bb2[tid];
    if (tid < NPB) hist[tid] = 0;
    __syncthreads();

    // ---- rank pass: ONE LDS atomic per record ----
    int rk[PBC / 512];
#pragma unroll
    for (int j = 0; j < PBC / 512; j++) {
        int i = tid + j * 512;
        rk[j] = (i < n) ? atomicAdd(&hist[rc[j] >> 17], 1) : -1;
    }
    __syncthreads();

    // ---- wave-0 shuffle scan of 128 bins -> exclusive base ----
    if (tid < 64) {
        int v0 = hist[tid], v1 = hist[tid + 64];
        int s0 = v0, s1 = v1;
#pragma unroll
        for (int off = 1; off < 64; off <<= 1) {
            int t0 = __shfl_up(s0, off);
            int t1 = __shfl_up(s1, off);
            if (tid >= off) { s0 += t0; s1 += t1; }
        }
        int tot0 = __shfl(s0, 63);
        base[tid]      = s0 - v0;
        base[tid + 64] = tot0 + s1 - v1;
    }
    __syncthreads();

    // ---- placement, NO atomics ----
#pragma unroll
    for (int j = 0; j < PBC / 512; j++) {
        if (rk[j] >= 0)
            sorted[base[rc[j] >> 17] + rk[j]] = rc[j];
    }
    __syncthreads();

    // write back sorted (coalesced) + per-dst (base,cnt) for k_acc2
    for (int i = tid; i < n; i += 512) w[i] = sorted[i];
    if (tid < NPB)
        bbase[b * NPB + tid] = (unsigned)base[tid] | ((unsigned)hist[tid] << 16);

    // ---- per-dst team accumulate: 4 lanes/team, zero atomics ----
    int cbase = base[t], c = hist[t];
    for (int r0 = 0; r0 < c; r0 += 8) {
        int m = c - r0;
        uint2 vv[8];
#pragma unroll
        for (int j = 0; j < 8; j++) {
            unsigned src = (j < m) ? (sorted[cbase + r0 + j] & 0x1FFFF) : DUMMY_SRC;
            vv[j] = *(const uint2*)(srcf + (size_t)src * D_HID + l * 4);
        }
#pragma unroll
        for (int j = 0; j < 8; j++) {
            acc0 += bfu(vv[j].x & 0xFFFFu); acc1 += bfu(vv[j].x >> 16);
            acc2_ += bfu(vv[j].y & 0xFFFFu); acc3 += bfu(vv[j].y >> 16);
        }
    }

    // ---- ReLU + layer-2 fold on the in-register row ----
    float h0 = fmaxf(acc0, 0.f), h1 = fmaxf(acc1, 0.f);
    float h2 = fmaxf(acc2_, 0.f), h3 = fmaxf(acc3, 0.f);
    float pr[D_OUT], pp[D_OUT];
#pragma unroll
    for (int o = 0; o < D_OUT; o++) {
        const float* wr = &s_rel2[o * D_HID + l * 4];
        const float* wo = &s_root2[o * D_HID + l * 4];
        pr[o] = h0 * wr[0] + h1 * wr[1] + h2 * wr[2] + h3 * wr[3];
        pp[o] = h0 * wo[0] + h1 * wo[1] + h2 * wo[2] + h3 * wo[3];
    }
#pragma unroll
    for (int m = 1; m < 4; m <<= 1) {
        pr[0] += __shfl_xor(pr[0], m); pr[1] += __shfl_xor(pr[1], m);
        pp[0] += __shfl_xor(pp[0], m); pp[1] += __shfl_xor(pp[1], m);
    }
    if (l == 0) {
        if (node < N_NODES) {
            ((float2*)hr)[node]   = make_float2(pr[0], pr[1]);
            ((float2*)outv)[node] = make_float2(pp[0] + s_b2[0], pp[1] + s_b2[1]);
        } else if (node == N_NODES) {
            ((float2*)hr)[node] = make_float2(0.f, 0.f);   // dummy row
        }
    }
}

// ---------------------------------------------------------------------------
// Layer-2 accumulate: LDS-free. One block per bucket, one 4-lane team per
// dst; lanes read the team's CONTIGUOUS sorted run directly from global
// (4 records/lane-step, 16B per team, coalesced across the wave), gather
// float2 hr (L2-resident) 4-deep, shfl_xor 4-lane reduce, plain RMW.
// No LDS, no barrier -> blocks overlap freely with k_sortacc stragglers.
// ---------------------------------------------------------------------------
__global__ __launch_bounds__(512) void k_acc2(
    const unsigned* __restrict__ recs2, const unsigned* __restrict__ bbase,
    const float* __restrict__ hr, float* __restrict__ outv)
{
    int b = blockIdx.x, tid = threadIdx.x;
    int t = tid >> 2, l = tid & 3;
    unsigned pk = bbase[b * NPB + t];
    int cbase = (int)(pk & 0xFFFFu), c = (int)(pk >> 16);
    int node = b * NPB + t;
    const unsigned* rp = recs2 + (size_t)b * PBC;

    float ax = 0.f, ay = 0.f;
    for (int r0 = 0; r0 < c; r0 += 16) {
        unsigned s4[4];
#pragma unroll
        for (int j = 0; j < 4; j++) {
            int idx = r0 + j * 4 + l;
            s4[j] = (idx < c) ? (rp[cbase + idx] & 0x1FFFF) : DUMMY_SRC;
        }
        float2 v4[4];
#pragma unroll
        for (int j = 0; j < 4; j++) v4[j] = ((const float2*)hr)[s4[j]];
#pragma unroll
        for (int j = 0; j < 4; j++) { ax += v4[j].x; ay += v4[j].y; }
    }
#pragma unroll
    for (int m = 1; m < 4; m <<= 1) {
        ax += __shfl_xor(ax, m); ay += __shfl_xor(ay, m);
    }
    if (l == 0 && node < N_NODES) {
        float2 o = ((const float2*)outv)[node];
        ((float2*)outv)[node] = make_float2(o.x + ax, o.y + ay);
    }
}

extern "C" void kernel_launch(void* const* d_in, const int* in_sizes, int n_in,
                              void* d_out, int out_size, void* d_ws, size_t ws_size,
                              hipStream_t stream) {
    const float* x       = (const float*)d_in[0];
    const int*   ei      = (const int*)  d_in[1];
    const float* w1_rel  = (const float*)d_in[2];
    const float* w1_root = (const float*)d_in[3];
    const float* b1      = (const float*)d_in[4];
    const float* w2_rel  = (const float*)d_in[5];
    const float* w2_root = (const float*)d_in[6];
    const float* b2      = (const float*)d_in[7];
    float* out = (float*)d_out;

    // Workspace (~19 MB; everything rewritten each call):
    float*          agg   = (float*)d_ws;                                   // NROWS*16 f32 (6.4 MB)
    unsigned short* xrh   = (unsigned short*)(agg + (size_t)NROWS * D_HID); // NROWS*16 bf16 (3.2 MB)
    unsigned*       recs2 = (unsigned*)(xrh + (size_t)NROWS * D_HID);       // NB*PBC (8.0 MB)
    float*          hr    = (float*)(recs2 + (size_t)NB * PBC);             // NROWS*2 f32 (0.8 MB)
    unsigned*       bbase = (unsigned*)(hr + (size_t)NROWS * D_OUT);        // NROWS u32 (0.4 MB)
    int*            gcur  = (int*)(bbase + (size_t)NROWS);                  // NB

    hipMemsetAsync(gcur, 0, NB * sizeof(int), stream);

    k_bin_node1<<<dim3(BBLOCKS), dim3(512), 0, stream>>>(
        ei, x, w1_rel, w1_root, b1, xrh, agg, gcur, recs2);

    k_sortacc<<<dim3(NB), dim3(512), 0, stream>>>(
        gcur, recs2, xrh, agg, w2_rel, w2_root, b2, hr, out, bbase);

    k_acc2<<<dim3(NB), dim3(512), 0, stream>>>(recs2, bbase, hr, out);
}